// Round 6
// baseline (2911.346 us; speedup 1.0000x reference)
//
#include <hip/hip_runtime.h>
#include <hip/hip_cooperative_groups.h>
#include <math.h>

namespace cg = cooperative_groups;

#define DC_C 6
#define NRANGE 8          // slot ranges, aligned to blockIdx%8 -> XCD round-robin
#define VCH 2048          // vars per block-chunk in inversion phase
#define NBLK 1024         // 4 blocks/CU at 256 CUs -- co-residency guaranteed
#define NTHR 256

// Per-check compressed message record (12 B = uint3, one dwordx3 gather).
// x = bits(Asp) = sprod*(relu(min2-b)-a)  [value on argmin edges]
// y = bits(Bsp) = sprod*(relu(min1-b)-a)  [value on other edges]
// z = masks: bits 0-5 amin, 8-13 negative-sign, 16-21 zero-sign
// c2v_j = sg_j * (amin_j ? Asp : Bsp), sg_j in {+1,-1,0}.

__device__ __forceinline__ float c2v_from_rec(uint3 r, int j) {
    float val = ((r.z >> j) & 1u) ? __uint_as_float(r.x) : __uint_as_float(r.y);
    float s = ((r.z >> (16 + j)) & 1u) ? 0.0f
            : (((r.z >> (8 + j)) & 1u) ? -1.0f : 1.0f);
    return s * val;
}

__global__ __launch_bounds__(NTHR, 4) void fused(
        const int* __restrict__ edge_chk,
        const float* __restrict__ llr,
        const float* __restrict__ beta,
        const float* __restrict__ alpha,
        int* __restrict__ cnt,
        unsigned long long* __restrict__ pos64,
        int* __restrict__ vmap,
        uint3* __restrict__ recs,
        float* __restrict__ p,
        float* __restrict__ out,
        int n, int n_chk, int E, int T) {
    cg::grid_group grid = cg::this_grid();
    const int tid = blockIdx.x * NTHR + threadIdx.x;
    const int nth = gridDim.x * NTHR;

    // ---- phase 0: clear slot counters (ws is poisoned every call) ----
    for (int c = tid; c < n_chk; c += nth) cnt[c] = 0;
    grid.sync();

    // ---- phase 1: slot assignment; pos64[v] = 3x21-bit slots ----
    for (int v = tid; v < n; v += nth) {
        int c0 = edge_chk[v * 3 + 0];
        int c1 = edge_chk[v * 3 + 1];
        int c2 = edge_chk[v * 3 + 2];
        int j0 = atomicAdd(&cnt[c0], 1);
        int j1 = atomicAdd(&cnt[c1], 1);
        int j2 = atomicAdd(&cnt[c2], 1);
        unsigned long long s0 = (unsigned long long)(c0 * DC_C + j0);
        unsigned long long s1 = (unsigned long long)(c1 * DC_C + j1);
        unsigned long long s2 = (unsigned long long)(c2 * DC_C + j2);
        pos64[v] = s0 | (s1 << 21) | (s2 << 42);
    }
    grid.sync();

    // ---- phase 2: invert pos64 -> vmap (slot -> var). Only random write;
    // range-partitioned so each vmap line fills from one XCD (blockIdx%8). ----
    {
        int r = (int)(blockIdx.x & (NRANGE - 1));
        int lo = r * (E / NRANGE);
        int hi = lo + (E / NRANGE);
        int nchunks = (n + VCH - 1) / VCH;
        for (int chunk = (int)(blockIdx.x >> 3); chunk < nchunks;
             chunk += (int)(gridDim.x >> 3)) {
            int base = chunk * VCH;
#pragma unroll
            for (int rr = 0; rr < VCH / NTHR; ++rr) {
                int v = base + rr * NTHR + (int)threadIdx.x;
                if (v < n) {
                    unsigned long long pk = pos64[v];
                    int s0 = (int)(pk & 0x1FFFFF);
                    int s1 = (int)((pk >> 21) & 0x1FFFFF);
                    int s2 = (int)((pk >> 42) & 0x1FFFFF);
                    if (s0 >= lo && s0 < hi) vmap[s0] = v;
                    if (s1 >= lo && s1 < hi) vmap[s1] = v;
                    if (s2 >= lo && s2 < hi) vmap[s2] = v;
                }
            }
        }
    }
    grid.sync();

    // ---- iterations ----
    for (int t = 0; t < T; ++t) {
        const float b = beta[t];
        const float a = alpha[t];
        const float* __restrict__ src = (t == 0) ? llr : p;  // p_0 == llr
        const bool first = (t == 0);                          // c2v_0 == 0

        // check phase: coalesced vmap + own old record; p-gather (2 MB, L2)
        for (int c = tid; c < n_chk; c += nth) {
            int base = c * DC_C;
            int2 w01 = *(const int2*)(vmap + base);
            int2 w23 = *(const int2*)(vmap + base + 2);
            int2 w45 = *(const int2*)(vmap + base + 4);
            int w[DC_C] = {w01.x, w01.y, w23.x, w23.y, w45.x, w45.y};
            float pv[DC_C];
#pragma unroll
            for (int j = 0; j < DC_C; ++j) pv[j] = src[w[j]];

            float old_[DC_C];
            if (first) {
#pragma unroll
                for (int j = 0; j < DC_C; ++j) old_[j] = 0.0f;
            } else {
                uint3 rec = recs[c];
#pragma unroll
                for (int j = 0; j < DC_C; ++j) old_[j] = c2v_from_rec(rec, j);
            }

            float sprod = 1.0f;
            float m1 = INFINITY, m2 = INFINITY;
            float mg[DC_C];
            unsigned int ng = 0, zr = 0;
#pragma unroll
            for (int j = 0; j < DC_C; ++j) {
                float x = pv[j] - old_[j];
                float m = fabsf(x);
                mg[j] = m;
                if (x < 0.0f) { ng |= (1u << j); sprod = -sprod; }
                else if (x == 0.0f) { zr |= (1u << j); sprod = 0.0f; }
                if (m < m1) { m2 = m1; m1 = m; }
                else if (m < m2) { m2 = m; }
            }
            unsigned int am = 0;
#pragma unroll
            for (int j = 0; j < DC_C; ++j) am |= (mg[j] == m1) ? (1u << j) : 0u;
            // ties: multiple amin bits imply m2==m1 -> A==B, identical to the
            // reference's first-argmin rule.
            float A = fmaxf(m2 - b, 0.0f) - a;
            float B = fmaxf(m1 - b, 0.0f) - a;
            recs[c] = make_uint3(__float_as_uint(sprod * A),
                                 __float_as_uint(sprod * B),
                                 am | (ng << 8) | (zr << 16));
        }
        grid.sync();

        if (t + 1 < T) {
            // var phase: coalesced pos64+llr, 3 record gathers (3 MB, L2)
            for (int v = tid; v < n; v += nth) {
                unsigned long long pk = pos64[v];
                int s0 = (int)(pk & 0x1FFFFF);
                int s1 = (int)((pk >> 21) & 0x1FFFFF);
                int s2 = (int)((pk >> 42) & 0x1FFFFF);
                uint3 r0 = recs[s0 / DC_C];
                uint3 r1 = recs[s1 / DC_C];
                uint3 r2 = recs[s2 / DC_C];
                float c0 = c2v_from_rec(r0, s0 % DC_C);
                float c1 = c2v_from_rec(r1, s1 % DC_C);
                float c2 = c2v_from_rec(r2, s2 % DC_C);
                p[v] = llr[v] + ((c0 + c1) + c2);
            }
            grid.sync();
        } else {
            // final: posterior + hard decision
            for (int v = tid; v < n; v += nth) {
                unsigned long long pk = pos64[v];
                int s0 = (int)(pk & 0x1FFFFF);
                int s1 = (int)((pk >> 21) & 0x1FFFFF);
                int s2 = (int)((pk >> 42) & 0x1FFFFF);
                uint3 r0 = recs[s0 / DC_C];
                uint3 r1 = recs[s1 / DC_C];
                uint3 r2 = recs[s2 / DC_C];
                float c0 = c2v_from_rec(r0, s0 % DC_C);
                float c1 = c2v_from_rec(r1, s1 % DC_C);
                float c2 = c2v_from_rec(r2, s2 % DC_C);
                float post = llr[v] + ((c0 + c1) + c2);
                out[v] = (post < 0.0f) ? 1.0f : 0.0f;
                out[n + v] = post;
            }
        }
    }
}

extern "C" void kernel_launch(void* const* d_in, const int* in_sizes, int n_in,
                              void* d_out, int out_size, void* d_ws, size_t ws_size,
                              hipStream_t stream) {
    const int* edge_chk   = (const int*)d_in[4];
    const float* llr      = (const float*)d_in[0];
    const float* beta     = (const float*)d_in[1];
    const float* alpha    = (const float*)d_in[2];

    int n  = in_sizes[0];       // 524288
    int T  = in_sizes[1];       // 10
    int E  = in_sizes[3];       // 1572864
    int n_chk = E / DC_C;       // 262144

    // Workspace (rebuilt every call; ws re-poisoned between calls)
    char* ws = (char*)d_ws;
    int*                cnt   = (int*)ws;                             // 1 MB @ 0
    unsigned long long* pos64 = (unsigned long long*)(ws + (1u << 20)); // 4 MB @ 1
    int*                vmap  = (int*)(ws + (5u << 20));              // 6 MB @ 5
    uint3*              recs  = (uint3*)(ws + (11u << 20));           // 3 MB @ 11
    float*              p     = (float*)(ws + (14u << 20));           // 2 MB @ 14
    float*              out   = (float*)d_out;

    void* args[] = {
        (void*)&edge_chk, (void*)&llr, (void*)&beta, (void*)&alpha,
        (void*)&cnt, (void*)&pos64, (void*)&vmap, (void*)&recs, (void*)&p,
        (void*)&out, (void*)&n, (void*)&n_chk, (void*)&E, (void*)&T,
    };
    hipLaunchCooperativeKernel((const void*)fused, dim3(NBLK), dim3(NTHR),
                               args, 0, stream);
}

// Round 7
// 366.566 us; speedup vs baseline: 7.9422x; 7.9422x over previous
//
#include <hip/hip_runtime.h>
#include <math.h>

#define DC_C 6
#define NRANGE 8          // slot ranges, aligned to blockIdx%8 -> XCD round-robin
#define VCH 2048          // vars per block-chunk in build_b

// Per-check compressed message record (12 B = uint3, one dwordx3 gather).
// x = bits(Asp) = sprod*(relu(min2-b)-a)  [value on argmin edges]
// y = bits(Bsp) = sprod*(relu(min1-b)-a)  [value on other edges]
// z = masks: bits 0-5 amin, 8-13 negative-sign, 16-21 zero-sign
// c2v_j = sg_j * (amin_j ? Asp : Bsp), sg_j in {+1,-1,0}.

__device__ __forceinline__ float c2v_from_rec(uint3 r, int j) {
    float val = ((r.z >> j) & 1u) ? __uint_as_float(r.x) : __uint_as_float(r.y);
    float s = ((r.z >> (16 + j)) & 1u) ? 0.0f
            : (((r.z >> (8 + j)) & 1u) ? -1.0f : 1.0f);
    return s * val;
}

// Phase A: slot assignment with nibble-packed counters. 8 checks share one
// 32-bit word (4 bits each; per-check count <= 6 so nibbles never carry).
// cnt footprint: 1 MB -> 128 KB; each atomic's word absorbs 8x more updates.
__global__ void build_a(const int* __restrict__ edge_chk,
                        unsigned int* __restrict__ cnt8,
                        unsigned long long* __restrict__ pos64,
                        int n) {
    int v = blockIdx.x * blockDim.x + threadIdx.x;
    if (v >= n) return;
    int c0 = edge_chk[v * 3 + 0];
    int c1 = edge_chk[v * 3 + 1];
    int c2 = edge_chk[v * 3 + 2];
    unsigned int sh0 = (c0 & 7) * 4, sh1 = (c1 & 7) * 4, sh2 = (c2 & 7) * 4;
    unsigned int o0 = atomicAdd(&cnt8[c0 >> 3], 1u << sh0);
    unsigned int o1 = atomicAdd(&cnt8[c1 >> 3], 1u << sh1);
    unsigned int o2 = atomicAdd(&cnt8[c2 >> 3], 1u << sh2);
    int j0 = (o0 >> sh0) & 0xF;
    int j1 = (o1 >> sh1) & 0xF;
    int j2 = (o2 >> sh2) & 0xF;
    unsigned long long s0 = (unsigned long long)(c0 * DC_C + j0);
    unsigned long long s1 = (unsigned long long)(c1 * DC_C + j1);
    unsigned long long s2 = (unsigned long long)(c2 * DC_C + j2);
    pos64[v] = s0 | (s1 << 21) | (s2 << 42);
}

// Phase B: invert pos64 -> vmap (slot -> variable). Only random write in the
// pipeline; range-partitioned so each vmap line is filled from one XCD
// (blockIdx%8 heuristic; perf-only, correctness-independent).
__global__ void build_b(const unsigned long long* __restrict__ pos64,
                        int* __restrict__ vmap,
                        int n, int E) {
    int r = blockIdx.x & (NRANGE - 1);
    int chunk = blockIdx.x >> 3;
    int lo = r * (E / NRANGE);
    int hi = lo + (E / NRANGE);
    int base = chunk * VCH;
#pragma unroll
    for (int rr = 0; rr < VCH / 256; ++rr) {
        int v = base + rr * 256 + threadIdx.x;
        if (v >= n) break;
        unsigned long long pk = pos64[v];
        int s0 = (int)(pk & 0x1FFFFF);
        int s1 = (int)((pk >> 21) & 0x1FFFFF);
        int s2 = (int)((pk >> 42) & 0x1FFFFF);
        if (s0 >= lo && s0 < hi) vmap[s0] = v;
        if (s1 >= lo && s1 < hi) vmap[s1] = v;
        if (s2 >= lo && s2 < hi) vmap[s2] = v;
    }
}

// Check-node update. Thread c:
//   coalesced: vmap[6c..6c+5] (3x int2), own old record (uint3), new record
//   random:    p[var_j] gathers from 2 MB (per-XCD L2-resident)
// v2c_j = p[w_j] - c2v_old_j; at t=0 (first=1): p==llr, c2v_old==0.
__global__ void check_kernel(const float* __restrict__ p,     // llr at t=0
                             const int* __restrict__ vmap,
                             uint3* __restrict__ recs,
                             const float* __restrict__ beta,
                             const float* __restrict__ alpha,
                             int t, int n_chk, int first) {
    int c = blockIdx.x * blockDim.x + threadIdx.x;
    if (c >= n_chk) return;
    int base = c * DC_C;
    int2 w01 = *(const int2*)(vmap + base);
    int2 w23 = *(const int2*)(vmap + base + 2);
    int2 w45 = *(const int2*)(vmap + base + 4);
    int w[DC_C] = {w01.x, w01.y, w23.x, w23.y, w45.x, w45.y};
    float pv[DC_C];
#pragma unroll
    for (int j = 0; j < DC_C; ++j) pv[j] = p[w[j]];

    float old_[DC_C];
    if (first) {
#pragma unroll
        for (int j = 0; j < DC_C; ++j) old_[j] = 0.0f;
    } else {
        uint3 rec = recs[c];
#pragma unroll
        for (int j = 0; j < DC_C; ++j) old_[j] = c2v_from_rec(rec, j);
    }

    float b = beta[t];
    float a = alpha[t];
    float sprod = 1.0f;
    float m1 = INFINITY, m2 = INFINITY;
    float mg[DC_C];
    unsigned int ng = 0, zr = 0;
#pragma unroll
    for (int j = 0; j < DC_C; ++j) {
        float x = pv[j] - old_[j];
        float m = fabsf(x);
        mg[j] = m;
        if (x < 0.0f) { ng |= (1u << j); sprod = -sprod; }
        else if (x == 0.0f) { zr |= (1u << j); sprod = 0.0f; }
        if (m < m1) { m2 = m1; m1 = m; }
        else if (m < m2) { m2 = m; }
    }
    unsigned int am = 0;
#pragma unroll
    for (int j = 0; j < DC_C; ++j) am |= (mg[j] == m1) ? (1u << j) : 0u;
    // ties: multiple amin bits imply m2==m1 -> A==B, identical to the
    // reference's first-argmin rule.
    float A = fmaxf(m2 - b, 0.0f) - a;
    float B = fmaxf(m1 - b, 0.0f) - a;
    recs[c] = make_uint3(__float_as_uint(sprod * A),
                         __float_as_uint(sprod * B),
                         am | (ng << 8) | (zr << 16));
}

// Variable-node update, 2 vars/thread for doubled gather MLP.
// Coalesced: pos64 (ulonglong2), llr (float2), p write (float2).
// Random: 6 record gathers from 3 MB L2-resident recs.
__global__ void var_kernel(const uint3* __restrict__ recs,
                           const unsigned long long* __restrict__ pos64,
                           const float* __restrict__ llr,
                           float* __restrict__ p,
                           int n2) {       // n/2
    int i = blockIdx.x * blockDim.x + threadIdx.x;
    if (i >= n2) return;
    ulonglong2 pk2 = *(const ulonglong2*)(pos64 + i * 2);
    float2 ll = *(const float2*)(llr + i * 2);
    int a0 = (int)(pk2.x & 0x1FFFFF);
    int a1 = (int)((pk2.x >> 21) & 0x1FFFFF);
    int a2 = (int)((pk2.x >> 42) & 0x1FFFFF);
    int b0 = (int)(pk2.y & 0x1FFFFF);
    int b1 = (int)((pk2.y >> 21) & 0x1FFFFF);
    int b2 = (int)((pk2.y >> 42) & 0x1FFFFF);
    uint3 ra0 = recs[a0 / DC_C];
    uint3 ra1 = recs[a1 / DC_C];
    uint3 ra2 = recs[a2 / DC_C];
    uint3 rb0 = recs[b0 / DC_C];
    uint3 rb1 = recs[b1 / DC_C];
    uint3 rb2 = recs[b2 / DC_C];
    float ca0 = c2v_from_rec(ra0, a0 % DC_C);
    float ca1 = c2v_from_rec(ra1, a1 % DC_C);
    float ca2 = c2v_from_rec(ra2, a2 % DC_C);
    float cb0 = c2v_from_rec(rb0, b0 % DC_C);
    float cb1 = c2v_from_rec(rb1, b1 % DC_C);
    float cb2 = c2v_from_rec(rb2, b2 % DC_C);
    float2 o;
    o.x = ll.x + ((ca0 + ca1) + ca2);
    o.y = ll.y + ((cb0 + cb1) + cb2);
    *(float2*)(p + i * 2) = o;
}

// Final: posterior + hard decision, 2 vars/thread.
// out[0..n)=bits(f32 0/1), out[n..2n)=posterior.
__global__ void final_kernel(const uint3* __restrict__ recs,
                             const unsigned long long* __restrict__ pos64,
                             const float* __restrict__ llr,
                             float* __restrict__ out,
                             int n2, int n) {
    int i = blockIdx.x * blockDim.x + threadIdx.x;
    if (i >= n2) return;
    ulonglong2 pk2 = *(const ulonglong2*)(pos64 + i * 2);
    float2 ll = *(const float2*)(llr + i * 2);
    int a0 = (int)(pk2.x & 0x1FFFFF);
    int a1 = (int)((pk2.x >> 21) & 0x1FFFFF);
    int a2 = (int)((pk2.x >> 42) & 0x1FFFFF);
    int b0 = (int)(pk2.y & 0x1FFFFF);
    int b1 = (int)((pk2.y >> 21) & 0x1FFFFF);
    int b2 = (int)((pk2.y >> 42) & 0x1FFFFF);
    uint3 ra0 = recs[a0 / DC_C];
    uint3 ra1 = recs[a1 / DC_C];
    uint3 ra2 = recs[a2 / DC_C];
    uint3 rb0 = recs[b0 / DC_C];
    uint3 rb1 = recs[b1 / DC_C];
    uint3 rb2 = recs[b2 / DC_C];
    float pa = ll.x + ((c2v_from_rec(ra0, a0 % DC_C)
                      + c2v_from_rec(ra1, a1 % DC_C))
                      + c2v_from_rec(ra2, a2 % DC_C));
    float pb = ll.y + ((c2v_from_rec(rb0, b0 % DC_C)
                      + c2v_from_rec(rb1, b1 % DC_C))
                      + c2v_from_rec(rb2, b2 % DC_C));
    float2 bits, post;
    bits.x = (pa < 0.0f) ? 1.0f : 0.0f;
    bits.y = (pb < 0.0f) ? 1.0f : 0.0f;
    post.x = pa;
    post.y = pb;
    *(float2*)(out + i * 2) = bits;
    *(float2*)(out + n + i * 2) = post;
}

extern "C" void kernel_launch(void* const* d_in, const int* in_sizes, int n_in,
                              void* d_out, int out_size, void* d_ws, size_t ws_size,
                              hipStream_t stream) {
    const float* llr      = (const float*)d_in[0];
    const float* beta     = (const float*)d_in[1];
    const float* alpha    = (const float*)d_in[2];
    const int*   edge_chk = (const int*)d_in[4];

    const int n  = in_sizes[0];       // 524288
    const int T  = in_sizes[1];       // 10
    const int E  = in_sizes[3];       // 1572864
    const int n_chk = E / DC_C;       // 262144

    // Workspace (rebuilt every call; ws re-poisoned between calls)
    char* ws = (char*)d_ws;
    unsigned int*       cnt8  = (unsigned int*)ws;                    // 128 KB @ 0
    unsigned long long* pos64 = (unsigned long long*)(ws + (1u << 20)); // 4 MB @ 1
    int*                vmap  = (int*)(ws + (5u << 20));              // 6 MB @ 5
    uint3*              recs  = (uint3*)(ws + (11u << 20));           // 3 MB @ 11
    float*              p     = (float*)(ws + (14u << 20));           // 2 MB @ 14

    hipMemsetAsync(cnt8, 0, (size_t)(n_chk / 8) * 4, stream);
    build_a<<<(n + 255) / 256, 256, 0, stream>>>(edge_chk, cnt8, pos64, n);
    {
        int chunks = (n + VCH - 1) / VCH;
        build_b<<<chunks * NRANGE, 256, 0, stream>>>(pos64, vmap, n, E);
    }
    for (int t = 0; t < T; ++t) {
        const float* src = (t == 0) ? llr : p;   // p_init == llr, c2v_0 == 0
        check_kernel<<<(n_chk + 255) / 256, 256, 0, stream>>>(
            src, vmap, recs, beta, alpha, t, n_chk, (t == 0) ? 1 : 0);
        if (t + 1 < T) {
            var_kernel<<<(n / 2 + 255) / 256, 256, 0, stream>>>(
                recs, pos64, llr, p, n / 2);
        } else {
            final_kernel<<<(n / 2 + 255) / 256, 256, 0, stream>>>(
                recs, pos64, llr, (float*)d_out, n / 2, n);
        }
    }
}